// Round 1
// 2425.951 us; speedup vs baseline: 1.1338x; 1.1338x over previous
//
#include <hip/hip_runtime.h>

typedef unsigned int uint;
typedef unsigned short ushort;

using bf16x8 = __attribute__((ext_vector_type(8))) short;
using f32x4  = __attribute__((ext_vector_type(4))) float;

#define LOAD16(g, l) __builtin_amdgcn_global_load_lds( \
    (const __attribute__((address_space(1))) void*)(g), \
    (__attribute__((address_space(3))) void*)(l), 16, 0, 0)

__device__ __forceinline__ ushort f2b(float f){
  uint u = __float_as_uint(f);
  u = (u + 0x7FFFu + ((u >> 16) & 1u)) >> 16;
  return (ushort)u;
}
__device__ __forceinline__ float b2f(ushort h){
  return __uint_as_float(((uint)h) << 16);
}
// mish(v) = v*tanh(softplus(v)) = v * t(t+2)/(t(t+2)+2), t=e^v  (exact algebra)
__device__ __forceinline__ float mishf(float v){
  float t = __expf(v);
  float u = t * (t + 2.f);
  float r = u * __builtin_amdgcn_rcpf(u + 2.f);
  return v > 15.f ? v : v * r;   // large-v: tanh(sp)==1 to fp32; also guards t^2 overflow
}

// ---------------- weight transpose + cast: W (K x N f32) -> Wt (N x K bf16) ----
__global__ __launch_bounds__(256) void transpose_f32_bf16(
    const float* __restrict__ W, ushort* __restrict__ Wt, int K, int N)
{
  __shared__ float tile[32][33];
  int k0 = blockIdx.x * 32, n0 = blockIdx.y * 32;
  int tx = threadIdx.x & 31, ty = threadIdx.x >> 5;
  #pragma unroll
  for (int r = ty; r < 32; r += 8)
    tile[r][tx] = W[(size_t)(k0 + r) * N + n0 + tx];
  __syncthreads();
  #pragma unroll
  for (int r = ty; r < 32; r += 8)
    Wt[(size_t)(n0 + r) * K + k0 + tx] = f2b(tile[tx][r]);
}

// ---------------- mish(c) -> bf16 -------------------------------------------
__global__ void mish_to_bf16(const float* __restrict__ in, ushort* __restrict__ out, int n){
  int i = blockIdx.x * blockDim.x + threadIdx.x;
  int stride = gridDim.x * blockDim.x;
  for (; i < n; i += stride) out[i] = f2b(mishf(in[i]));
}

// ---------------- LayerNorm + modulate -> bf16 -------------------------------
__global__ __launch_bounds__(256) void ln_modulate(
    const float* __restrict__ xin,   // R x 768
    const float* __restrict__ modb,  // mod + b0*4608
    ushort* __restrict__ out,        // R x 768 bf16
    int shift_off, int scale_off)
{
  int row = blockIdx.x;
  int t = threadIdx.x;
  const float* xr = xin + (size_t)row * 768;
  float v0 = xr[t], v1 = xr[t + 256], v2 = xr[t + 512];
  float s  = v0 + v1 + v2;
  float ss = v0*v0 + v1*v1 + v2*v2;
  #pragma unroll
  for (int off = 32; off > 0; off >>= 1){
    s  += __shfl_down(s, off);
    ss += __shfl_down(ss, off);
  }
  __shared__ float rs[4], rss[4];
  int wave = t >> 6, lane = t & 63;
  if (lane == 0){ rs[wave] = s; rss[wave] = ss; }
  __syncthreads();
  s  = rs[0] + rs[1] + rs[2] + rs[3];
  ss = rss[0] + rss[1] + rss[2] + rss[3];
  float mean = s * (1.f / 768.f);
  float var  = ss * (1.f / 768.f) - mean * mean;
  float rstd = rsqrtf(var + 1e-5f);
  const float* mr = modb + (size_t)(row >> 6) * 4608;
  ushort* orow = out + (size_t)row * 768;
  #pragma unroll
  for (int e = 0; e < 3; e++){
    int n = t + e * 256;
    float xv = (e == 0 ? v0 : (e == 1 ? v1 : v2));
    float sc = 1.f + mr[scale_off + n];
    float sh = mr[shift_off + n];
    orow[n] = f2b((xv - mean) * rstd * sc + sh);
  }
}

// ---------------- GEMM: C = A(MxK,bf16) * Bt(NxK,bf16)^T + bias, fused epilogue
// Double-buffered LDS (2-phase T3 template): loads for tile t+1 are issued
// BEFORE the ds_read+MFMA of tile t, so the vmcnt drain at the single
// end-of-iter barrier happens after ~400cy of compute — global->LDS latency
// hidden within one block instead of exposed per K-step.
// XOR-swizzled LDS layout unchanged:
//   LDS slot (row, c) [c = 16B chunk 0..3 within a 32-bf16 K-slab] holds
//   global chunk c ^ ((row>>1)&3).  Fragment read at chunk q reads slot
//   q ^ ((row>>1)&3) -> global chunk q.
// MODE 0: out_f = v
// MODE 1: out_h = bf16(v)
// MODE 2: out_f = resid + gate * v     (gate[(m>>6)*4608 + n])
// MODE 3: out_h = bf16(mish(v))
template<int MODE>
__global__ __launch_bounds__(256) void gemm_bt(
    const ushort* __restrict__ A,
    const ushort* __restrict__ Bt,
    const float* __restrict__ bias,
    float* __restrict__ out_f,
    ushort* __restrict__ out_h,
    const float* __restrict__ resid,
    const float* __restrict__ gate,
    int M, int N, int K)
{
  __shared__ ushort sA[2][128 * 32];
  __shared__ ushort sB[2][128 * 32];
  int tid  = threadIdx.x;
  int lane = tid & 63, wave = tid >> 6;
  int l15  = lane & 15, quad = lane >> 4;
  int m0 = blockIdx.x * 128, n0 = blockIdx.y * 128;
  int wm = (wave & 1) * 64, wn = (wave >> 1) * 64;

  // staging: wave w stages rows [w*32, w*32+32); 2 issues per matrix
  int r0  = wave * 32 + (lane >> 2);
  int r1  = r0 + 16;
  int cs  = lane & 3;
  int kc0 = cs ^ ((r0 >> 1) & 3);
  int kc1 = cs ^ ((r1 >> 1) & 3);
  const ushort* gA0 = A  + (size_t)(m0 + r0) * K + kc0 * 8;
  const ushort* gA1 = A  + (size_t)(m0 + r1) * K + kc1 * 8;
  const ushort* gB0 = Bt + (size_t)(n0 + r0) * K + kc0 * 8;
  const ushort* gB1 = Bt + (size_t)(n0 + r1) * K + kc1 * 8;
  int wofs = wave * 1024;

  // fragment read offsets (swizzled chunk)
  int sw = quad ^ ((l15 >> 1) & 3);
  int ra = (wm + l15) * 32 + sw * 8;
  int rb = (wn + l15) * 32 + sw * 8;

  f32x4 acc[4][4];
  #pragma unroll
  for (int i = 0; i < 4; i++)
    #pragma unroll
    for (int j = 0; j < 4; j++) acc[i][j] = (f32x4){0.f, 0.f, 0.f, 0.f};

  int nk = K >> 5;

  // prologue: stage tile 0 into buffer 0
  LOAD16(gA0, &sA[0][wofs]);
  LOAD16(gA1, &sA[0][wofs + 512]);
  LOAD16(gB0, &sB[0][wofs]);
  LOAD16(gB1, &sB[0][wofs + 512]);
  gA0 += 32; gA1 += 32; gB0 += 32; gB1 += 32;
  __syncthreads();                       // tile 0 resident

  for (int kt = 0; kt < nk - 1; kt++){
    int cur = kt & 1, nxt = cur ^ 1;
    // issue next tile's loads first — in flight across the compute phase
    LOAD16(gA0, &sA[nxt][wofs]);
    LOAD16(gA1, &sA[nxt][wofs + 512]);
    LOAD16(gB0, &sB[nxt][wofs]);
    LOAD16(gB1, &sB[nxt][wofs + 512]);
    gA0 += 32; gA1 += 32; gB0 += 32; gB1 += 32;

    bf16x8 af[4], bv[4];
    #pragma unroll
    for (int i = 0; i < 4; i++) af[i] = *(const bf16x8*)(&sA[cur][ra + i * 512]);
    #pragma unroll
    for (int j = 0; j < 4; j++) bv[j] = *(const bf16x8*)(&sB[cur][rb + j * 512]);
    #pragma unroll
    for (int i = 0; i < 4; i++)
      #pragma unroll
      for (int j = 0; j < 4; j++)
        acc[i][j] = __builtin_amdgcn_mfma_f32_16x16x32_bf16(af[i], bv[j], acc[i][j], 0, 0, 0);

    __syncthreads();   // drains vmcnt (next tile ready) + lgkmcnt (cur reads done)
  }

  { // epilogue tile: compute only
    int cur = (nk - 1) & 1;
    bf16x8 af[4], bv[4];
    #pragma unroll
    for (int i = 0; i < 4; i++) af[i] = *(const bf16x8*)(&sA[cur][ra + i * 512]);
    #pragma unroll
    for (int j = 0; j < 4; j++) bv[j] = *(const bf16x8*)(&sB[cur][rb + j * 512]);
    #pragma unroll
    for (int i = 0; i < 4; i++)
      #pragma unroll
      for (int j = 0; j < 4; j++)
        acc[i][j] = __builtin_amdgcn_mfma_f32_16x16x32_bf16(af[i], bv[j], acc[i][j], 0, 0, 0);
  }

  float bias_v[4];
  #pragma unroll
  for (int j = 0; j < 4; j++) bias_v[j] = bias[n0 + wn + j * 16 + l15];
  #pragma unroll
  for (int i = 0; i < 4; i++){
    int mb = m0 + wm + i * 16 + quad * 4;
    #pragma unroll
    for (int j = 0; j < 4; j++){
      int n = n0 + wn + j * 16 + l15;
      #pragma unroll
      for (int r = 0; r < 4; r++){
        int m = mb + r;
        float v = acc[i][j][r] + bias_v[j];
        size_t idx = (size_t)m * N + n;
        if (MODE == 0)      out_f[idx] = v;
        else if (MODE == 1) out_h[idx] = f2b(v);
        else if (MODE == 2){
          float g = gate[(size_t)(m >> 6) * 4608 + n];
          out_f[idx] = resid[idx] + g * v;
        } else              out_h[idx] = f2b(mishf(v));
      }
    }
  }
}

// ---------------- attention: one block per (batch-in-chunk, head) ------------
__global__ __launch_bounds__(256) void attn64(
    const ushort* __restrict__ qkv,
    ushort* __restrict__ out)        // RC x 768 bf16
{
  __shared__ float kk[64][68];
  __shared__ float vv[64][68];
  __shared__ float sc[64][65];
  __shared__ float red[2][4][64];
  int bi = blockIdx.x, h = blockIdx.y;
  int t  = threadIdx.x;
  int s4 = t >> 2, p = t & 3;
  size_t rowbase = ((size_t)bi * 64 + s4) * 2304 + h * 64;

  {
    const uint4* kp = (const uint4*)(qkv + rowbase + 768  + p * 16);
    const uint4* vp = (const uint4*)(qkv + rowbase + 1536 + p * 16);
    union { uint4 u; ushort s[8]; } k0, k1, v0, v1;
    k0.u = kp[0]; k1.u = kp[1]; v0.u = vp[0]; v1.u = vp[1];
    #pragma unroll
    for (int e = 0; e < 8; e++){
      kk[s4][p * 16 + e]     = b2f(k0.s[e]);
      kk[s4][p * 16 + 8 + e] = b2f(k1.s[e]);
      vv[s4][p * 16 + e]     = b2f(v0.s[e]);
      vv[s4][p * 16 + 8 + e] = b2f(v1.s[e]);
    }
  }
  float qr[64];
  {
    const uint4* qp = (const uint4*)(qkv + rowbase);
    #pragma unroll
    for (int c = 0; c < 8; c++){
      union { uint4 u; ushort s[8]; } q; q.u = qp[c];
      #pragma unroll
      for (int e = 0; e < 8; e++) qr[c * 8 + e] = b2f(q.s[e]);
    }
  }
  __syncthreads();

  float scr[16]; float mx = -1e30f;
  #pragma unroll
  for (int jj = 0; jj < 16; jj++){
    int j = p * 16 + jj;
    float a = 0.f;
    #pragma unroll
    for (int d = 0; d < 64; d++) a += qr[d] * kk[j][d];
    a *= 0.125f;
    scr[jj] = a; mx = fmaxf(mx, a);
  }
  red[0][p][s4] = mx;
  __syncthreads();
  float rmx = fmaxf(fmaxf(red[0][0][s4], red[0][1][s4]),
                    fmaxf(red[0][2][s4], red[0][3][s4]));
  float sm = 0.f;
  #pragma unroll
  for (int jj = 0; jj < 16; jj++){
    float e = __expf(scr[jj] - rmx);
    sm += e;
    sc[s4][p * 16 + jj] = e;
  }
  red[1][p][s4] = sm;
  __syncthreads();
  float rinv = 1.f / (red[1][0][s4] + red[1][1][s4] + red[1][2][s4] + red[1][3][s4]);

  float o[16];
  #pragma unroll
  for (int e = 0; e < 16; e++) o[e] = 0.f;
  for (int j = 0; j < 64; j++){
    float pj = sc[s4][j];
    #pragma unroll
    for (int e = 0; e < 16; e++) o[e] += pj * vv[j][p * 16 + e];
  }
  ushort* op = out + ((size_t)bi * 64 + s4) * 768 + h * 64 + p * 16;
  #pragma unroll
  for (int e = 0; e < 16; e++) op[e] = f2b(o[e] * rinv);
}

// -----------------------------------------------------------------------------
extern "C" void kernel_launch(void* const* d_in, const int* in_sizes, int n_in,
                              void* d_out, int out_size, void* d_ws, size_t ws_size,
                              hipStream_t stream)
{
  (void)in_sizes; (void)n_in; (void)out_size; (void)ws_size;
  const float* x     = (const float*)d_in[0];
  const float* c     = (const float*)d_in[1];
  const float* W_mod = (const float*)d_in[2];
  const float* b_mod = (const float*)d_in[3];
  const float* W_qkv = (const float*)d_in[4];
  const float* b_qkv = (const float*)d_in[5];
  const float* W_out = (const float*)d_in[6];
  const float* b_out = (const float*)d_in[7];
  const float* W_f1  = (const float*)d_in[8];
  const float* b_f1  = (const float*)d_in[9];
  const float* W_f2  = (const float*)d_in[10];
  const float* b_f2  = (const float*)d_in[11];
  float* out = (float*)d_out;

  char* ws = (char*)d_ws;
  size_t off = 0;
  auto alloc = [&](size_t bytes)->char* {
    char* p = ws + off; off += (bytes + 255) & ~(size_t)255; return p;
  };
  ushort* Wb_mod = (ushort*)alloc((size_t)768 * 4608 * 2);
  ushort* Wb_qkv = (ushort*)alloc((size_t)768 * 2304 * 2);
  ushort* Wb_out = (ushort*)alloc((size_t)768 * 768  * 2);
  ushort* Wb_f1  = (ushort*)alloc((size_t)768 * 3072 * 2);
  ushort* Wb_f2  = (ushort*)alloc((size_t)3072 * 768 * 2);
  ushort* c_act  = (ushort*)alloc((size_t)1024 * 768 * 2);
  float*  mod    = (float*) alloc((size_t)1024 * 4608 * 4);
  ushort* bufH   = (ushort*)alloc((size_t)16384 * 768  * 2);
  ushort* bufQKV = (ushort*)alloc((size_t)16384 * 2304 * 2);
  ushort* bufG   = (ushort*)alloc((size_t)16384 * 3072 * 2);

  transpose_f32_bf16<<<dim3(24, 144), 256, 0, stream>>>(W_mod, Wb_mod, 768, 4608);
  transpose_f32_bf16<<<dim3(24, 72),  256, 0, stream>>>(W_qkv, Wb_qkv, 768, 2304);
  transpose_f32_bf16<<<dim3(24, 24),  256, 0, stream>>>(W_out, Wb_out, 768, 768);
  transpose_f32_bf16<<<dim3(24, 96),  256, 0, stream>>>(W_f1,  Wb_f1,  768, 3072);
  transpose_f32_bf16<<<dim3(96, 24),  256, 0, stream>>>(W_f2,  Wb_f2,  3072, 768);
  mish_to_bf16<<<512, 256, 0, stream>>>(c, c_act, 1024 * 768);
  gemm_bt<0><<<dim3(8, 36), 256, 0, stream>>>(c_act, Wb_mod, b_mod, mod, nullptr,
                                              nullptr, nullptr, 1024, 4608, 768);

  for (int ch = 0; ch < 4; ch++){
    int b0 = ch * 256;
    const float* xc   = x   + (size_t)b0 * 64 * 768;
    float*       oc   = out + (size_t)b0 * 64 * 768;
    const float* modc = mod + (size_t)b0 * 4608;

    ln_modulate<<<16384, 256, 0, stream>>>(xc, modc, bufH, 0, 768);
    gemm_bt<1><<<dim3(128, 18), 256, 0, stream>>>(bufH, Wb_qkv, b_qkv, nullptr, bufQKV,
                                                  nullptr, nullptr, 16384, 2304, 768);
    attn64<<<dim3(256, 12), 256, 0, stream>>>(bufQKV, bufH);
    gemm_bt<2><<<dim3(128, 6), 256, 0, stream>>>(bufH, Wb_out, b_out, oc, nullptr,
                                                 xc, modc + 1536, 16384, 768, 768);
    ln_modulate<<<16384, 256, 0, stream>>>(oc, modc, bufH, 2304, 3072);
    gemm_bt<3><<<dim3(128, 24), 256, 0, stream>>>(bufH, Wb_f1, b_f1, nullptr, bufG,
                                                  nullptr, nullptr, 16384, 3072, 768);
    gemm_bt<2><<<dim3(128, 6), 256, 0, stream>>>(bufG, Wb_f2, b_f2, oc, nullptr,
                                                 oc, modc + 3840, 16384, 768, 3072);
  }
}